// Round 8
// baseline (319.805 us; speedup 1.0000x reference)
//
#include <hip/hip_runtime.h>
#include <math.h>

#define BB 8
#define HH 512
#define WW 1024
#define HW (HH * WW)          // 524288 = 2^19
#define NPIX (BB * HW)        // 4194304
#define NSEG 16               // segments 1..16 (0 skipped)
#define SUPPRESS 0.1f

// ws layout (bytes):
//   moments4 : double[4][8][16][14] @ 0      (57344)   4-way spread partials
//   res4     : double[4][8][16]     @ 57344  (4096)
//   scal64   : double[64][4]        @ 61440  (2048)    [dx,dy,Sb,Sbf] partials
//   maxfg64  : unsigned[64]         @ 63488  (256)
//   params   : float[128*6]         @ 63744  (3072)
//   valid    : int[128]             @ 66816  (512)

__device__ __forceinline__ float wave_sum(float t) {
    #pragma unroll
    for (int off = 32; off > 0; off >>= 1) t += __shfl_down(t, off);
    return t;
}

#define REP8(M) M(0) M(1) M(2) M(3) M(4) M(5) M(6) M(7)
#define REP16(M) M(0) M(1) M(2) M(3) M(4) M(5) M(6) M(7) \
                 M(8) M(9) M(10) M(11) M(12) M(13) M(14) M(15)

// ---------------- K_M: segment moments, named-scalar accumulators ----------------
// r6/r7 lesson: runtime-indexed arrays -> scratch; default VGPR cap (64) for
// 512-thr blocks -> spills (r7 WRITE_SIZE 28.6MB). Fix: launch_bounds(512,1)
// lifts cap to 256; each wave owns ALL 16 segments of one feature group as
// named scalars (grp0: 64 f32, grp1: 80 f32). 8 waves = 4 rows x 2 groups.
// Feature groups: GRP0 {N,Sx,Sxx,Su}, GRP1 {Sv,Suu,Svv,Sxu,Sxv}.
// y-moments derived at flush: Sy=yN, Sxy=ySx, Syy=y^2N, Syu=ySu, Syv=ySv.
// moment order: [n,Sx,Sy,Sxx,Sxy,Syy,Su,Sv,Suu,Svv,Sxu,Syu,Sxv,Syv]
__device__ __forceinline__ void mom_grp0(
    const float* __restrict__ fuR, const int* __restrict__ mkR,
    int lane, double* __restrict__ cell, double yd)
{
#define DECL0(i) float n_##i = 0.f, sx_##i = 0.f, sxx_##i = 0.f, su_##i = 0.f;
    REP16(DECL0)
    #pragma unroll
    for (int it = 0; it < 4; ++it) {
        const int o = it * 256 + lane * 4;
        const int4   m4 = *(const int4*)&mkR[o];
        const float4 u4 = *(const float4*)&fuR[o];
        const int   segs[4] = {m4.x, m4.y, m4.z, m4.w};
        const float us[4]   = {u4.x, u4.y, u4.z, u4.w};
        #pragma unroll
        for (int j = 0; j < 4; ++j) {
            const int   sr = segs[j] - 1;
            const float x  = (float)(o + j);
            const float xx = x * x;
            const float u  = us[j];
#define STEP0(i) { const float d = (sr == i) ? 1.f : 0.f; \
            n_##i += d; sx_##i = fmaf(d, x, sx_##i); \
            sxx_##i = fmaf(d, xx, sxx_##i); su_##i = fmaf(d, u, su_##i); }
            REP16(STEP0)
        }
    }
#define FIN0(i) { \
    const float N = wave_sum(n_##i), SX = wave_sum(sx_##i); \
    const float SXX = wave_sum(sxx_##i), SU = wave_sum(su_##i); \
    if (lane == 0) { \
        double* c = cell + i * 14; \
        atomicAdd(c + 0, (double)N); \
        atomicAdd(c + 1, (double)SX); \
        atomicAdd(c + 2, yd * (double)N); \
        atomicAdd(c + 3, (double)SXX); \
        atomicAdd(c + 4, yd * (double)SX); \
        atomicAdd(c + 5, yd * yd * (double)N); \
        atomicAdd(c + 6, (double)SU); \
        atomicAdd(c + 11, yd * (double)SU); } }
    REP16(FIN0)
}

__device__ __forceinline__ void mom_grp1(
    const float* __restrict__ fuR, const float* __restrict__ fvR,
    const int* __restrict__ mkR,
    int lane, double* __restrict__ cell, double yd)
{
#define DECL1(i) float sv_##i = 0.f, suu_##i = 0.f, svv_##i = 0.f, \
                       sxu_##i = 0.f, sxv_##i = 0.f;
    REP16(DECL1)
    #pragma unroll
    for (int it = 0; it < 4; ++it) {
        const int o = it * 256 + lane * 4;
        const int4   m4 = *(const int4*)&mkR[o];
        const float4 u4 = *(const float4*)&fuR[o];
        const float4 v4 = *(const float4*)&fvR[o];
        const int   segs[4] = {m4.x, m4.y, m4.z, m4.w};
        const float us[4]   = {u4.x, u4.y, u4.z, u4.w};
        const float vs[4]   = {v4.x, v4.y, v4.z, v4.w};
        #pragma unroll
        for (int j = 0; j < 4; ++j) {
            const int   sr = segs[j] - 1;
            const float x  = (float)(o + j);
            const float u  = us[j], v = vs[j];
            const float uu = u * u, vv = v * v, xu = x * u, xv = x * v;
#define STEP1(i) { const float d = (sr == i) ? 1.f : 0.f; \
            sv_##i = fmaf(d, v, sv_##i); suu_##i = fmaf(d, uu, suu_##i); \
            svv_##i = fmaf(d, vv, svv_##i); sxu_##i = fmaf(d, xu, sxu_##i); \
            sxv_##i = fmaf(d, xv, sxv_##i); }
            REP16(STEP1)
        }
    }
#define FIN1(i) { \
    const float SV = wave_sum(sv_##i), SUU = wave_sum(suu_##i); \
    const float SVV = wave_sum(svv_##i), SXU = wave_sum(sxu_##i); \
    const float SXV = wave_sum(sxv_##i); \
    if (lane == 0) { \
        double* c = cell + i * 14; \
        atomicAdd(c + 7, (double)SV); \
        atomicAdd(c + 8, (double)SUU); \
        atomicAdd(c + 9, (double)SVV); \
        atomicAdd(c + 10, (double)SXU); \
        atomicAdd(c + 12, (double)SXV); \
        atomicAdd(c + 13, yd * (double)SV); } }
    REP16(FIN1)
}

__global__ __launch_bounds__(512, 1) void moments_kernel(
    const float* __restrict__ flow,
    const int*   __restrict__ masks,
    double* __restrict__ moments4)    // [4][8*16*14]
{
    const int tid  = threadIdx.x;
    const int lane = tid & 63;
    const int wid  = tid >> 6;             // 0..7
    const int rowo = wid & 3;              // 4 rows per block
    const int grp  = wid >> 2;             // 2 feature groups

    const long long base = (long long)blockIdx.x * 4096;  // 4 rows per block
    const int b   = (int)(base >> 19);
    const int h0  = (int)((base & (HW - 1)) >> 10);
    const int row = h0 + rowo;
    const int par = blockIdx.x & 3;

    const float* fuR = flow + (long long)b * (2LL * HW) + row * WW;
    const float* fvR = fuR + HW;
    const int*   mkR = masks + (long long)b * HW + row * WW;
    double* cell = moments4 + par * 1792 + b * 224;
    const double yd = (double)row;

    if (grp == 0) mom_grp0(fuR, mkR, lane, cell, yd);
    else          mom_grp1(fuR, fvR, mkR, lane, cell, yd);
}

// ---------------- K_A: boundary, sobel, smooth (unchanged, validated) ----------------
__global__ __launch_bounds__(256) void stencil_kernel(
    const float* __restrict__ flow,
    const int*   __restrict__ masks,
    const float* __restrict__ images,
    double* __restrict__ scal64,      // [64][4]
    unsigned* __restrict__ maxfg64)   // [64]
{
    __shared__ float         sm[4][1032];
    __shared__ unsigned char smask[4][1032];
    __shared__ float         su[3][1024];
    __shared__ float         sv[3][1024];
    __shared__ float         sg[3][1024];
    __shared__ float         wred[4][5];

    const int tid = threadIdx.x;
    const int lane = tid & 63;
    const long long base = (long long)blockIdx.x * 2048;
    const int b  = (int)(base >> 19);
    const int h0 = (int)((base & (HW - 1)) >> 10);

    const float* fu = flow + (long long)b * (2LL * HW);
    const float* fv = fu + HW;
    const int*   mk = masks + (long long)b * HW;
    const float* i0 = images + (long long)b * (3LL * HW);
    const float* i1 = i0 + HW;
    const float* i2 = i1 + HW;

    const int c4 = tid * 4;
    #pragma unroll
    for (int r = 0; r < 4; ++r) {
        const int gr = h0 - 1 + r;
        const int mr = gr < 0 ? 0 : (gr > HH - 1 ? HH - 1 : gr);
        const int4 mv = *(const int4*)&mk[mr * WW + c4];
        uchar4 mb;
        mb.x = (unsigned char)mv.x; mb.y = (unsigned char)mv.y;
        mb.z = (unsigned char)mv.z; mb.w = (unsigned char)mv.w;
        *(uchar4*)&smask[r][4 + c4] = mb;

        float4 u4 = make_float4(0.f, 0.f, 0.f, 0.f);
        float4 v4 = make_float4(0.f, 0.f, 0.f, 0.f);
        if (gr >= 0 && gr <= HH - 1) {
            u4 = *(const float4*)&fu[gr * WW + c4];
            v4 = *(const float4*)&fv[gr * WW + c4];
        }
        float4 m4;
        m4.x = sqrtf(u4.x * u4.x + v4.x * v4.x);
        m4.y = sqrtf(u4.y * u4.y + v4.y * v4.y);
        m4.z = sqrtf(u4.z * u4.z + v4.z * v4.z);
        m4.w = sqrtf(u4.w * u4.w + v4.w * v4.w);
        *(float4*)&sm[r][4 + c4] = m4;
        if (r >= 1) {
            *(float4*)&su[r - 1][c4] = u4;
            *(float4*)&sv[r - 1][c4] = v4;
        }
    }
    #pragma unroll
    for (int r = 0; r < 3; ++r) {
        const int gr = h0 + r;
        float4 g4 = make_float4(0.f, 0.f, 0.f, 0.f);
        if (gr <= HH - 1) {
            const float4 a  = *(const float4*)&i0[gr * WW + c4];
            const float4 bq = *(const float4*)&i1[gr * WW + c4];
            const float4 c  = *(const float4*)&i2[gr * WW + c4];
            g4.x = (a.x + bq.x + c.x) * (1.f / 3.f);
            g4.y = (a.y + bq.y + c.y) * (1.f / 3.f);
            g4.z = (a.z + bq.z + c.z) * (1.f / 3.f);
            g4.w = (a.w + bq.w + c.w) * (1.f / 3.f);
        }
        *(float4*)&sg[r][c4] = g4;
    }
    if (tid < 4) {
        const int gr = h0 - 1 + tid;
        const int mr = gr < 0 ? 0 : (gr > HH - 1 ? HH - 1 : gr);
        smask[tid][3]    = (unsigned char)mk[mr * WW + 0];
        smask[tid][1028] = (unsigned char)mk[mr * WW + WW - 1];
        sm[tid][3] = 0.f;
        sm[tid][1028] = 0.f;
    }
    __syncthreads();

    float a_dx = 0.f, a_dy = 0.f, a_sb = 0.f, a_sbf = 0.f, mfg = 0.f;

    #pragma unroll
    for (int it = 0; it < 8; ++it) {
        const int idx = it * 256 + tid;
        const int lr = idx >> 10;
        const int w  = idx & 1023;
        const int h  = h0 + lr;
        const int cc = 4 + w;

        const int segc = smask[lr + 1][cc];
        int bnd = (smask[lr][cc - 1] != segc) | (smask[lr][cc] != segc) |
                  (smask[lr][cc + 1] != segc) |
                  (smask[lr + 1][cc - 1] != segc) | (smask[lr + 1][cc + 1] != segc) |
                  (smask[lr + 2][cc - 1] != segc) | (smask[lr + 2][cc] != segc) |
                  (smask[lr + 2][cc + 1] != segc);

        const float t00 = sm[lr][cc - 1],     t01 = sm[lr][cc],     t02 = sm[lr][cc + 1];
        const float t10 = sm[lr + 1][cc - 1],                       t12 = sm[lr + 1][cc + 1];
        const float t20 = sm[lr + 2][cc - 1], t21 = sm[lr + 2][cc], t22 = sm[lr + 2][cc + 1];
        const float fgx = (t02 - t00) + 2.f * (t12 - t10) + (t22 - t20);
        const float fgy = (t20 + 2.f * t21 + t22) - (t00 + 2.f * t01 + t02);
        const float fgraw = fabsf(fgx) + fabsf(fgy);
        mfg = fmaxf(mfg, fgraw);
        if (bnd) { a_sb += 1.f; a_sbf += fgraw; }

        const float u = su[lr][w], v = sv[lr][w];
        const float g0 = sg[lr][w];
        if (w < WW - 1) {
            const float wgt = expf(-fabsf(sg[lr][w + 1] - g0) * 10.f) * (bnd ? SUPPRESS : 1.f);
            a_dx += (fabsf(su[lr][w + 1] - u) + fabsf(sv[lr][w + 1] - v)) * wgt;
        }
        if (h < HH - 1) {
            const float wgt = expf(-fabsf(sg[lr + 1][w] - g0) * 10.f) * (bnd ? SUPPRESS : 1.f);
            a_dy += (fabsf(su[lr + 1][w] - u) + fabsf(sv[lr + 1][w] - v)) * wgt;
        }
    }

    for (int off = 32; off > 0; off >>= 1) {
        a_dx += __shfl_down(a_dx, off);
        a_dy += __shfl_down(a_dy, off);
        a_sb += __shfl_down(a_sb, off);
        a_sbf += __shfl_down(a_sbf, off);
        mfg = fmaxf(mfg, __shfl_down(mfg, off));
    }
    if (lane == 0) {
        const int wv = tid >> 6;
        wred[wv][0] = a_dx; wred[wv][1] = a_dy; wred[wv][2] = a_sb;
        wred[wv][3] = a_sbf; wred[wv][4] = mfg;
    }
    __syncthreads();
    if (tid == 0) {
        float dx = 0.f, dy = 0.f, sb = 0.f, sbf = 0.f, mf = 0.f;
        for (int i = 0; i < 4; ++i) {
            dx += wred[i][0]; dy += wred[i][1]; sb += wred[i][2];
            sbf += wred[i][3]; mf = fmaxf(mf, wred[i][4]);
        }
        const int sl = blockIdx.x & 63;
        atomicAdd(&scal64[sl * 4 + 0], (double)dx);
        atomicAdd(&scal64[sl * 4 + 1], (double)dy);
        atomicAdd(&scal64[sl * 4 + 2], (double)sb);
        atomicAdd(&scal64[sl * 4 + 3], (double)sbf);
        atomicMax(&maxfg64[sl], __float_as_uint(mf));
    }
}

// ---------------- solve: sum partials, 3x3 normal equations + variance ----------------
__global__ __launch_bounds__(128) void solve_kernel(
    const double* __restrict__ moments4,
    float* __restrict__ params,   // [128][6]
    int* __restrict__ valid,      // [128]
    float* __restrict__ out)
{
    const int i = threadIdx.x;    // (b, seg-1)
    double m[14];
    #pragma unroll
    for (int k = 0; k < 14; ++k) {
        double s = 0.0;
        #pragma unroll
        for (int par = 0; par < 4; ++par) s += moments4[par * 1792 + i * 14 + k];
        m[k] = s;
    }
    const double n = m[0];
    const int vh = (n >= 100.0) ? 1 : 0;
    float p[6] = {0.f, 0.f, 0.f, 0.f, 0.f, 0.f};
    if (vh) {
        double A[3][3] = {{m[3], m[4], m[1]},
                          {m[4], m[5], m[2]},
                          {m[1], m[2], n}};
        double Bm[3][2] = {{m[10], m[12]},
                           {m[11], m[13]},
                           {m[6],  m[7]}};
        for (int k = 0; k < 3; ++k) {
            int piv = k; double mx = fabs(A[k][k]);
            for (int r = k + 1; r < 3; ++r) {
                double a = fabs(A[r][k]);
                if (a > mx) { mx = a; piv = r; }
            }
            if (piv != k) {
                for (int c = 0; c < 3; ++c) { double t = A[k][c]; A[k][c] = A[piv][c]; A[piv][c] = t; }
                for (int c = 0; c < 2; ++c) { double t = Bm[k][c]; Bm[k][c] = Bm[piv][c]; Bm[piv][c] = t; }
            }
            const double inv = 1.0 / A[k][k];
            for (int r = k + 1; r < 3; ++r) {
                const double f = A[r][k] * inv;
                for (int c = k; c < 3; ++c) A[r][c] -= f * A[k][c];
                Bm[r][0] -= f * Bm[k][0];
                Bm[r][1] -= f * Bm[k][1];
            }
        }
        double X[3][2];
        for (int c = 0; c < 2; ++c) {
            X[2][c] = Bm[2][c] / A[2][2];
            X[1][c] = (Bm[1][c] - A[1][2] * X[2][c]) / A[1][1];
            X[0][c] = (Bm[0][c] - A[0][1] * X[1][c] - A[0][2] * X[2][c]) / A[0][0];
        }
        p[0] = (float)X[0][0]; p[1] = (float)X[1][0]; p[2] = (float)X[2][0];
        p[3] = (float)X[0][1]; p[4] = (float)X[1][1]; p[5] = (float)X[2][1];
    }
    valid[i] = vh;
    for (int c = 0; c < 6; ++c) params[i * 6 + c] = p[c];

    const int vv = (n >= 50.0) ? 1 : 0;
    double var = 0.0;
    if (vv) {
        const double ns = (n > 2.0) ? n : 2.0;
        const double var_u = (m[8] - m[6] * m[6] / ns) / (ns - 1.0);
        const double var_v = (m[9] - m[7] * m[7] / ns) / (ns - 1.0);
        var = var_u + var_v;
    }
    __shared__ double svar[128];
    __shared__ int scnt[128];
    svar[i] = var; scnt[i] = vv;
    __syncthreads();
    for (int s = 64; s > 0; s >>= 1) {
        if (i < s) { svar[i] += svar[i + s]; scnt[i] += scnt[i + s]; }
        __syncthreads();
    }
    if (i == 0) out[2] = (float)(svar[0] / (double)(scnt[0] > 1 ? scnt[0] : 1));
}

// ---------------- pass 2: residuals, named-scalar accumulators ----------------
__global__ __launch_bounds__(256) void pass2_kernel(
    const float* __restrict__ flow,
    const int*   __restrict__ masks,
    const float* __restrict__ params,
    double* __restrict__ res4)        // [4][8][16]
{
    __shared__ float sp[17 * 6];      // row 0 = zeros (background)

    const long long base = (long long)blockIdx.x * 4096;
    const int b      = (int)(base >> 19);
    const int hwbase = (int)(base & (HW - 1));
    const int tid    = threadIdx.x;
    const int lane   = tid & 63;

    if (tid < 6) sp[tid] = 0.f;
    if (tid < 96) sp[6 + tid] = params[b * 96 + tid];
    __syncthreads();

    const float* fu = flow + (long long)b * (2LL * HW);
    const float* fv = fu + HW;
    const int*   mk = masks + (long long)b * HW;

#define DECLR(i) float r_##i = 0.f;
    REP8(DECLR)
#define DECLR2(i) float q_##i = 0.f;
    REP8(DECLR2)

    #pragma unroll
    for (int it = 0; it < 4; ++it) {
        const int i4 = hwbase + it * 1024 + tid * 4;
        const int4   m4 = *(const int4*)&mk[i4];
        const float4 u4 = *(const float4*)&fu[i4];
        const float4 v4 = *(const float4*)&fv[i4];
        const int segs[4] = {m4.x, m4.y, m4.z, m4.w};
        const float us[4] = {u4.x, u4.y, u4.z, u4.w};
        const float vs[4] = {v4.x, v4.y, v4.z, v4.w};
        #pragma unroll
        for (int j = 0; j < 4; ++j) {
            const int seg = segs[j];
            const float* pf = &sp[seg * 6];
            const int hw = i4 + j;
            const float x = (float)(hw & 1023), y = (float)((hw & (HW - 1)) >> 10);
            const float du = us[j] - (x * pf[0] + y * pf[1] + pf[2]);
            const float dv = vs[j] - (x * pf[3] + y * pf[4] + pf[5]);
            const float r = sqrtf(du * du + dv * dv);
            const int sr = seg - 1;
#define STEPR(i) r_##i += (sr == i) ? r : 0.f;
            REP8(STEPR)
#define STEPR2(i) q_##i += (sr == 8 + i) ? r : 0.f;
            REP8(STEPR2)
        }
    }

    const int par = blockIdx.x & 3;
    double* rb = &res4[par * 128 + b * 16];
#define FINR(i) { const float s = wave_sum(r_##i); \
    if (lane == 0) atomicAdd(rb + i, (double)s); }
    REP8(FINR)
#define FINR2(i) { const float s = wave_sum(q_##i); \
    if (lane == 0) atomicAdd(rb + 8 + i, (double)s); }
    REP8(FINR2)
}

// ---------------- finalize: homog, sharp, smooth ----------------
__global__ __launch_bounds__(128) void final_kernel(
    const double* __restrict__ moments4,
    const double* __restrict__ res4,
    const int*    __restrict__ valid,
    const double* __restrict__ scal64,
    const unsigned* __restrict__ maxfg64,
    float* __restrict__ out)
{
    const int i = threadIdx.x;
    double n = 0.0, rs = 0.0;
    #pragma unroll
    for (int par = 0; par < 4; ++par) {
        n  += moments4[par * 1792 + i * 14];
        rs += res4[par * 128 + i];
    }
    const int vh = valid[i];
    const double rm = vh ? rs / (n > 1.0 ? n : 1.0) : 0.0;
    __shared__ double sr[128];
    __shared__ int sc[128];
    sr[i] = rm; sc[i] = vh;
    __syncthreads();
    for (int s = 64; s > 0; s >>= 1) {
        if (i < s) { sr[i] += sr[i + s]; sc[i] += sc[i + s]; }
        __syncthreads();
    }
    if (i == 0) {
        out[0] = (float)(sr[0] / (double)(sc[0] > 1 ? sc[0] : 1));
        double dx = 0.0, dy = 0.0, sb = 0.0, sbf = 0.0;
        float mf = 0.f;
        for (int k = 0; k < 64; ++k) {
            dx += scal64[k * 4 + 0]; dy += scal64[k * 4 + 1];
            sb += scal64[k * 4 + 2]; sbf += scal64[k * 4 + 3];
            mf = fmaxf(mf, __uint_as_float(maxfg64[k]));
        }
        const double maxfg = (double)mf;
        const double maxb = (sb > 0.0) ? 1.0 : 0.0;
        out[1] = (float)((sb - sbf / (maxfg + 1e-6)) / (maxb + 1e-6) / (double)NPIX);
        const double smooth = dx / (double)(2LL * BB * HH * (WW - 1)) +
                              dy / (double)(2LL * BB * (HH - 1) * WW);
        out[3] = (float)smooth;
    }
}

extern "C" void kernel_launch(void* const* d_in, const int* in_sizes, int n_in,
                              void* d_out, int out_size, void* d_ws, size_t ws_size,
                              hipStream_t stream)
{
    const float* flow   = (const float*)d_in[0];
    const int*   masks  = (const int*)d_in[1];
    const float* images = (const float*)d_in[2];
    float* out = (float*)d_out;

    char* ws = (char*)d_ws;
    double*   moments4 = (double*)(ws);             // 0     .. 57344
    double*   res4     = (double*)(ws + 57344);     // 57344 .. 61440
    double*   scal64   = (double*)(ws + 61440);     // 61440 .. 63488
    unsigned* maxfg64  = (unsigned*)(ws + 63488);   // 63488 .. 63744
    float*    params   = (float*)(ws + 63744);      // 63744 .. 66816
    int*      valid    = (int*)(ws + 66816);        // 66816 .. 67328

    hipMemsetAsync(d_ws, 0, 67584, stream);

    moments_kernel<<<dim3(NPIX / 4096), dim3(512), 0, stream>>>(flow, masks, moments4);
    stencil_kernel<<<dim3(NPIX / 2048), dim3(256), 0, stream>>>(
        flow, masks, images, scal64, maxfg64);
    solve_kernel<<<dim3(1), dim3(128), 0, stream>>>(moments4, params, valid, out);
    pass2_kernel<<<dim3(NPIX / 4096), dim3(256), 0, stream>>>(
        flow, masks, params, res4);
    final_kernel<<<dim3(1), dim3(128), 0, stream>>>(
        moments4, res4, valid, scal64, maxfg64, out);
}

// Round 9
// 147.534 us; speedup vs baseline: 2.1677x; 2.1677x over previous
//
#include <hip/hip_runtime.h>
#include <math.h>

#define BB 8
#define HH 512
#define WW 1024
#define HW (HH * WW)          // 524288 = 2^19
#define NPIX (BB * HW)        // 4194304
#define NSEG 16               // segments 1..16 (0 skipped)
#define SUPPRESS 0.1f

// ws layout (bytes):
//   moments4 : double[4][8][16][14] @ 0      (57344)   4-way spread partials
//   res4     : double[4][8][16]     @ 57344  (4096)
//   scal64   : double[64][4]        @ 61440  (2048)    [dx,dy,Sb,Sbf] partials
//   maxfg64  : unsigned[64]         @ 63488  (256)
//   params   : float[128*6]         @ 63744  (3072)
//   valid    : int[128]             @ 66816  (512)

__device__ __forceinline__ float wave_sum(float t) {
    #pragma unroll
    for (int off = 32; off > 0; off >>= 1) t += __shfl_down(t, off);
    return t;
}

#define REP8(M) M(0) M(1) M(2) M(3) M(4) M(5) M(6) M(7)

// ---------------- K_M: segment moments via lane-private LDS bins ----------------
// r4-r8 lessons: LDS atomics ~190cy/wave-inst (r4); register delta-predication
// costs 16x duplication (224 ops/px) and big unrolls thrash I$ (r8). Fix: bins
// in LDS are runtime-INDEXABLE and lane-private (no atomics, no conflicts:
// addr = seg*576 + feat*64 + lane; 576 % 32 == 0 so banks follow lane).
// Block = 1 wave = 64col x 64row tile; lane = column -> x const per lane,
// y wave-uniform per row. Bin only 9 features {n,Sy,Syy,Su,Sv,Suu,Svv,Syu,Syv};
// x-moments fold at epilogue: Sx=sum(x*n), Sxx=sum(x^2*n), Sxy=sum(x*sy),
// Sxu=sum(x*su), Sxv=sum(x*sv). seg==0 goes to a dummy bin (no divergence).
// moment order: [n,Sx,Sy,Sxx,Sxy,Syy,Su,Sv,Suu,Svv,Sxu,Syu,Sxv,Syv]
__global__ __launch_bounds__(64) void moments_kernel(
    const float* __restrict__ flow,
    const int*   __restrict__ masks,
    double* __restrict__ moments4)    // [4][8*16*14]
{
    __shared__ float bins[9984];      // 17*9*64 = 9792, padded to 39*256

    const int lane = threadIdx.x;
    const int bid  = blockIdx.x;      // 1024 = 8 batches x 8 rowgrps x 16 colgrps
    const int colg = bid & 15;
    const int rowg = (bid >> 4) & 7;
    const int b    = bid >> 7;
    const int par  = bid & 3;

    const int c0 = colg * 64;
    const int r0 = rowg * 64;
    const float x = (float)(c0 + lane);

    const float* fu = flow + (long long)b * (2LL * HW);
    const float* fv = fu + HW;
    const int*   mk = masks + (long long)b * HW;
    const int*   mrow = mk + r0 * WW + c0 + lane;
    const float* urow = fu + r0 * WW + c0 + lane;
    const float* vrow = fv + r0 * WW + c0 + lane;

    // zero bins: 39 float4 stores per lane
    #pragma unroll
    for (int i = 0; i < 39; ++i)
        *(float4*)&bins[i * 256 + lane * 4] = make_float4(0.f, 0.f, 0.f, 0.f);

    // depth-2 software prefetch (rows r+2, r+3 in flight)
    int   m0 = mrow[0];
    float u0 = urow[0], v0 = vrow[0];
    int   m1 = mrow[WW];
    float u1 = urow[WW], v1 = vrow[WW];

    #pragma unroll 1
    for (int r = 0; r < 64; r += 2) {
        const int o2 = ((r + 2) & 63) * WW;   // wraps at end; values unused
        const int o3 = ((r + 3) & 63) * WW;
        const int   m2 = mrow[o2];
        const float u2 = urow[o2], v2 = vrow[o2];
        const int   m3 = mrow[o3];
        const float u3 = urow[o3], v3 = vrow[o3];

        {
            const float y = (float)(r0 + r);
            float* bp = &bins[m0 * 576 + lane];
            float b0 = bp[0],   b1 = bp[64],  b2 = bp[128];
            float b3 = bp[192], b4 = bp[256], b5 = bp[320];
            float b6 = bp[384], b7 = bp[448], b8 = bp[512];
            b0 += 1.f;
            b1 += y;
            b2 = fmaf(y, y, b2);
            b3 += u0;
            b4 += v0;
            b5 = fmaf(u0, u0, b5);
            b6 = fmaf(v0, v0, b6);
            b7 = fmaf(y, u0, b7);
            b8 = fmaf(y, v0, b8);
            bp[0] = b0;   bp[64] = b1;  bp[128] = b2;
            bp[192] = b3; bp[256] = b4; bp[320] = b5;
            bp[384] = b6; bp[448] = b7; bp[512] = b8;
        }
        {
            const float y = (float)(r0 + r + 1);
            float* bp = &bins[m1 * 576 + lane];
            float b0 = bp[0],   b1 = bp[64],  b2 = bp[128];
            float b3 = bp[192], b4 = bp[256], b5 = bp[320];
            float b6 = bp[384], b7 = bp[448], b8 = bp[512];
            b0 += 1.f;
            b1 += y;
            b2 = fmaf(y, y, b2);
            b3 += u1;
            b4 += v1;
            b5 = fmaf(u1, u1, b5);
            b6 = fmaf(v1, v1, b6);
            b7 = fmaf(y, u1, b7);
            b8 = fmaf(y, v1, b8);
            bp[0] = b0;   bp[64] = b1;  bp[128] = b2;
            bp[192] = b3; bp[256] = b4; bp[320] = b5;
            bp[384] = b6; bp[448] = b7; bp[512] = b8;
        }
        m0 = m2; u0 = u2; v0 = v2;
        m1 = m3; u1 = u3; v1 = v3;
    }

    // epilogue: lane-sum each bin, folding x where needed; skip dummy seg 0
    double* cell = moments4 + par * 1792 + b * 224;
    #pragma unroll 1
    for (int s = 1; s <= 16; ++s) {
        const float* bp = &bins[s * 576 + lane];
        const float n = bp[0],    sy = bp[64],  syy = bp[128];
        const float su = bp[192], sv = bp[256], suu = bp[320];
        const float svv = bp[384], syu = bp[448], syv = bp[512];
        const float N   = wave_sum(n);
        const float SX  = wave_sum(x * n);
        const float SY  = wave_sum(sy);
        const float SXX = wave_sum(x * x * n);
        const float SXY = wave_sum(x * sy);
        const float SYY = wave_sum(syy);
        const float SU  = wave_sum(su);
        const float SV  = wave_sum(sv);
        const float SUU = wave_sum(suu);
        const float SVV = wave_sum(svv);
        const float SXU = wave_sum(x * su);
        const float SYU = wave_sum(syu);
        const float SXV = wave_sum(x * sv);
        const float SYV = wave_sum(syv);
        if (lane == 0) {
            double* c = cell + (s - 1) * 14;
            atomicAdd(c + 0,  (double)N);
            atomicAdd(c + 1,  (double)SX);
            atomicAdd(c + 2,  (double)SY);
            atomicAdd(c + 3,  (double)SXX);
            atomicAdd(c + 4,  (double)SXY);
            atomicAdd(c + 5,  (double)SYY);
            atomicAdd(c + 6,  (double)SU);
            atomicAdd(c + 7,  (double)SV);
            atomicAdd(c + 8,  (double)SUU);
            atomicAdd(c + 9,  (double)SVV);
            atomicAdd(c + 10, (double)SXU);
            atomicAdd(c + 11, (double)SYU);
            atomicAdd(c + 12, (double)SXV);
            atomicAdd(c + 13, (double)SYV);
        }
    }
}

// ---------------- K_A: boundary, sobel, smooth (unchanged, validated) ----------------
__global__ __launch_bounds__(256) void stencil_kernel(
    const float* __restrict__ flow,
    const int*   __restrict__ masks,
    const float* __restrict__ images,
    double* __restrict__ scal64,      // [64][4]
    unsigned* __restrict__ maxfg64)   // [64]
{
    __shared__ float         sm[4][1032];
    __shared__ unsigned char smask[4][1032];
    __shared__ float         su[3][1024];
    __shared__ float         sv[3][1024];
    __shared__ float         sg[3][1024];
    __shared__ float         wred[4][5];

    const int tid = threadIdx.x;
    const int lane = tid & 63;
    const long long base = (long long)blockIdx.x * 2048;
    const int b  = (int)(base >> 19);
    const int h0 = (int)((base & (HW - 1)) >> 10);

    const float* fu = flow + (long long)b * (2LL * HW);
    const float* fv = fu + HW;
    const int*   mk = masks + (long long)b * HW;
    const float* i0 = images + (long long)b * (3LL * HW);
    const float* i1 = i0 + HW;
    const float* i2 = i1 + HW;

    const int c4 = tid * 4;
    #pragma unroll
    for (int r = 0; r < 4; ++r) {
        const int gr = h0 - 1 + r;
        const int mr = gr < 0 ? 0 : (gr > HH - 1 ? HH - 1 : gr);
        const int4 mv = *(const int4*)&mk[mr * WW + c4];
        uchar4 mb;
        mb.x = (unsigned char)mv.x; mb.y = (unsigned char)mv.y;
        mb.z = (unsigned char)mv.z; mb.w = (unsigned char)mv.w;
        *(uchar4*)&smask[r][4 + c4] = mb;

        float4 u4 = make_float4(0.f, 0.f, 0.f, 0.f);
        float4 v4 = make_float4(0.f, 0.f, 0.f, 0.f);
        if (gr >= 0 && gr <= HH - 1) {
            u4 = *(const float4*)&fu[gr * WW + c4];
            v4 = *(const float4*)&fv[gr * WW + c4];
        }
        float4 m4;
        m4.x = sqrtf(u4.x * u4.x + v4.x * v4.x);
        m4.y = sqrtf(u4.y * u4.y + v4.y * v4.y);
        m4.z = sqrtf(u4.z * u4.z + v4.z * v4.z);
        m4.w = sqrtf(u4.w * u4.w + v4.w * v4.w);
        *(float4*)&sm[r][4 + c4] = m4;
        if (r >= 1) {
            *(float4*)&su[r - 1][c4] = u4;
            *(float4*)&sv[r - 1][c4] = v4;
        }
    }
    #pragma unroll
    for (int r = 0; r < 3; ++r) {
        const int gr = h0 + r;
        float4 g4 = make_float4(0.f, 0.f, 0.f, 0.f);
        if (gr <= HH - 1) {
            const float4 a  = *(const float4*)&i0[gr * WW + c4];
            const float4 bq = *(const float4*)&i1[gr * WW + c4];
            const float4 c  = *(const float4*)&i2[gr * WW + c4];
            g4.x = (a.x + bq.x + c.x) * (1.f / 3.f);
            g4.y = (a.y + bq.y + c.y) * (1.f / 3.f);
            g4.z = (a.z + bq.z + c.z) * (1.f / 3.f);
            g4.w = (a.w + bq.w + c.w) * (1.f / 3.f);
        }
        *(float4*)&sg[r][c4] = g4;
    }
    if (tid < 4) {
        const int gr = h0 - 1 + tid;
        const int mr = gr < 0 ? 0 : (gr > HH - 1 ? HH - 1 : gr);
        smask[tid][3]    = (unsigned char)mk[mr * WW + 0];
        smask[tid][1028] = (unsigned char)mk[mr * WW + WW - 1];
        sm[tid][3] = 0.f;
        sm[tid][1028] = 0.f;
    }
    __syncthreads();

    float a_dx = 0.f, a_dy = 0.f, a_sb = 0.f, a_sbf = 0.f, mfg = 0.f;

    #pragma unroll
    for (int it = 0; it < 8; ++it) {
        const int idx = it * 256 + tid;
        const int lr = idx >> 10;
        const int w  = idx & 1023;
        const int h  = h0 + lr;
        const int cc = 4 + w;

        const int segc = smask[lr + 1][cc];
        int bnd = (smask[lr][cc - 1] != segc) | (smask[lr][cc] != segc) |
                  (smask[lr][cc + 1] != segc) |
                  (smask[lr + 1][cc - 1] != segc) | (smask[lr + 1][cc + 1] != segc) |
                  (smask[lr + 2][cc - 1] != segc) | (smask[lr + 2][cc] != segc) |
                  (smask[lr + 2][cc + 1] != segc);

        const float t00 = sm[lr][cc - 1],     t01 = sm[lr][cc],     t02 = sm[lr][cc + 1];
        const float t10 = sm[lr + 1][cc - 1],                       t12 = sm[lr + 1][cc + 1];
        const float t20 = sm[lr + 2][cc - 1], t21 = sm[lr + 2][cc], t22 = sm[lr + 2][cc + 1];
        const float fgx = (t02 - t00) + 2.f * (t12 - t10) + (t22 - t20);
        const float fgy = (t20 + 2.f * t21 + t22) - (t00 + 2.f * t01 + t02);
        const float fgraw = fabsf(fgx) + fabsf(fgy);
        mfg = fmaxf(mfg, fgraw);
        if (bnd) { a_sb += 1.f; a_sbf += fgraw; }

        const float u = su[lr][w], v = sv[lr][w];
        const float g0 = sg[lr][w];
        if (w < WW - 1) {
            const float wgt = expf(-fabsf(sg[lr][w + 1] - g0) * 10.f) * (bnd ? SUPPRESS : 1.f);
            a_dx += (fabsf(su[lr][w + 1] - u) + fabsf(sv[lr][w + 1] - v)) * wgt;
        }
        if (h < HH - 1) {
            const float wgt = expf(-fabsf(sg[lr + 1][w] - g0) * 10.f) * (bnd ? SUPPRESS : 1.f);
            a_dy += (fabsf(su[lr + 1][w] - u) + fabsf(sv[lr + 1][w] - v)) * wgt;
        }
    }

    for (int off = 32; off > 0; off >>= 1) {
        a_dx += __shfl_down(a_dx, off);
        a_dy += __shfl_down(a_dy, off);
        a_sb += __shfl_down(a_sb, off);
        a_sbf += __shfl_down(a_sbf, off);
        mfg = fmaxf(mfg, __shfl_down(mfg, off));
    }
    if (lane == 0) {
        const int wv = tid >> 6;
        wred[wv][0] = a_dx; wred[wv][1] = a_dy; wred[wv][2] = a_sb;
        wred[wv][3] = a_sbf; wred[wv][4] = mfg;
    }
    __syncthreads();
    if (tid == 0) {
        float dx = 0.f, dy = 0.f, sb = 0.f, sbf = 0.f, mf = 0.f;
        for (int i = 0; i < 4; ++i) {
            dx += wred[i][0]; dy += wred[i][1]; sb += wred[i][2];
            sbf += wred[i][3]; mf = fmaxf(mf, wred[i][4]);
        }
        const int sl = blockIdx.x & 63;
        atomicAdd(&scal64[sl * 4 + 0], (double)dx);
        atomicAdd(&scal64[sl * 4 + 1], (double)dy);
        atomicAdd(&scal64[sl * 4 + 2], (double)sb);
        atomicAdd(&scal64[sl * 4 + 3], (double)sbf);
        atomicMax(&maxfg64[sl], __float_as_uint(mf));
    }
}

// ---------------- solve: sum partials, 3x3 normal equations + variance ----------------
__global__ __launch_bounds__(128) void solve_kernel(
    const double* __restrict__ moments4,
    float* __restrict__ params,   // [128][6]
    int* __restrict__ valid,      // [128]
    float* __restrict__ out)
{
    const int i = threadIdx.x;    // (b, seg-1)
    double m[14];
    #pragma unroll
    for (int k = 0; k < 14; ++k) {
        double s = 0.0;
        #pragma unroll
        for (int par = 0; par < 4; ++par) s += moments4[par * 1792 + i * 14 + k];
        m[k] = s;
    }
    const double n = m[0];
    const int vh = (n >= 100.0) ? 1 : 0;
    float p[6] = {0.f, 0.f, 0.f, 0.f, 0.f, 0.f};
    if (vh) {
        double A[3][3] = {{m[3], m[4], m[1]},
                          {m[4], m[5], m[2]},
                          {m[1], m[2], n}};
        double Bm[3][2] = {{m[10], m[12]},
                           {m[11], m[13]},
                           {m[6],  m[7]}};
        for (int k = 0; k < 3; ++k) {
            int piv = k; double mx = fabs(A[k][k]);
            for (int r = k + 1; r < 3; ++r) {
                double a = fabs(A[r][k]);
                if (a > mx) { mx = a; piv = r; }
            }
            if (piv != k) {
                for (int c = 0; c < 3; ++c) { double t = A[k][c]; A[k][c] = A[piv][c]; A[piv][c] = t; }
                for (int c = 0; c < 2; ++c) { double t = Bm[k][c]; Bm[k][c] = Bm[piv][c]; Bm[piv][c] = t; }
            }
            const double inv = 1.0 / A[k][k];
            for (int r = k + 1; r < 3; ++r) {
                const double f = A[r][k] * inv;
                for (int c = k; c < 3; ++c) A[r][c] -= f * A[k][c];
                Bm[r][0] -= f * Bm[k][0];
                Bm[r][1] -= f * Bm[k][1];
            }
        }
        double X[3][2];
        for (int c = 0; c < 2; ++c) {
            X[2][c] = Bm[2][c] / A[2][2];
            X[1][c] = (Bm[1][c] - A[1][2] * X[2][c]) / A[1][1];
            X[0][c] = (Bm[0][c] - A[0][1] * X[1][c] - A[0][2] * X[2][c]) / A[0][0];
        }
        p[0] = (float)X[0][0]; p[1] = (float)X[1][0]; p[2] = (float)X[2][0];
        p[3] = (float)X[0][1]; p[4] = (float)X[1][1]; p[5] = (float)X[2][1];
    }
    valid[i] = vh;
    for (int c = 0; c < 6; ++c) params[i * 6 + c] = p[c];

    const int vv = (n >= 50.0) ? 1 : 0;
    double var = 0.0;
    if (vv) {
        const double ns = (n > 2.0) ? n : 2.0;
        const double var_u = (m[8] - m[6] * m[6] / ns) / (ns - 1.0);
        const double var_v = (m[9] - m[7] * m[7] / ns) / (ns - 1.0);
        var = var_u + var_v;
    }
    __shared__ double svar[128];
    __shared__ int scnt[128];
    svar[i] = var; scnt[i] = vv;
    __syncthreads();
    for (int s = 64; s > 0; s >>= 1) {
        if (i < s) { svar[i] += svar[i + s]; scnt[i] += scnt[i + s]; }
        __syncthreads();
    }
    if (i == 0) out[2] = (float)(svar[0] / (double)(scnt[0] > 1 ? scnt[0] : 1));
}

// ---------------- pass 2: residuals, named-scalar accumulators ----------------
__global__ __launch_bounds__(256) void pass2_kernel(
    const float* __restrict__ flow,
    const int*   __restrict__ masks,
    const float* __restrict__ params,
    double* __restrict__ res4)        // [4][8][16]
{
    __shared__ float sp[17 * 6];      // row 0 = zeros (background)

    const long long base = (long long)blockIdx.x * 4096;
    const int b      = (int)(base >> 19);
    const int hwbase = (int)(base & (HW - 1));
    const int tid    = threadIdx.x;
    const int lane   = tid & 63;

    if (tid < 6) sp[tid] = 0.f;
    if (tid < 96) sp[6 + tid] = params[b * 96 + tid];
    __syncthreads();

    const float* fu = flow + (long long)b * (2LL * HW);
    const float* fv = fu + HW;
    const int*   mk = masks + (long long)b * HW;

#define DECLR(i) float r_##i = 0.f;
    REP8(DECLR)
#define DECLR2(i) float q_##i = 0.f;
    REP8(DECLR2)

    #pragma unroll
    for (int it = 0; it < 4; ++it) {
        const int i4 = hwbase + it * 1024 + tid * 4;
        const int4   m4 = *(const int4*)&mk[i4];
        const float4 u4 = *(const float4*)&fu[i4];
        const float4 v4 = *(const float4*)&fv[i4];
        const int segs[4] = {m4.x, m4.y, m4.z, m4.w};
        const float us[4] = {u4.x, u4.y, u4.z, u4.w};
        const float vs[4] = {v4.x, v4.y, v4.z, v4.w};
        #pragma unroll
        for (int j = 0; j < 4; ++j) {
            const int seg = segs[j];
            const float* pf = &sp[seg * 6];
            const int hw = i4 + j;
            const float x = (float)(hw & 1023), y = (float)((hw & (HW - 1)) >> 10);
            const float du = us[j] - (x * pf[0] + y * pf[1] + pf[2]);
            const float dv = vs[j] - (x * pf[3] + y * pf[4] + pf[5]);
            const float r = sqrtf(du * du + dv * dv);
            const int sr = seg - 1;
#define STEPR(i) r_##i += (sr == i) ? r : 0.f;
            REP8(STEPR)
#define STEPR2(i) q_##i += (sr == 8 + i) ? r : 0.f;
            REP8(STEPR2)
        }
    }

    const int par = blockIdx.x & 3;
    double* rb = &res4[par * 128 + b * 16];
#define FINR(i) { const float s = wave_sum(r_##i); \
    if (lane == 0) atomicAdd(rb + i, (double)s); }
    REP8(FINR)
#define FINR2(i) { const float s = wave_sum(q_##i); \
    if (lane == 0) atomicAdd(rb + 8 + i, (double)s); }
    REP8(FINR2)
}

// ---------------- finalize: homog, sharp, smooth ----------------
__global__ __launch_bounds__(128) void final_kernel(
    const double* __restrict__ moments4,
    const double* __restrict__ res4,
    const int*    __restrict__ valid,
    const double* __restrict__ scal64,
    const unsigned* __restrict__ maxfg64,
    float* __restrict__ out)
{
    const int i = threadIdx.x;
    double n = 0.0, rs = 0.0;
    #pragma unroll
    for (int par = 0; par < 4; ++par) {
        n  += moments4[par * 1792 + i * 14];
        rs += res4[par * 128 + i];
    }
    const int vh = valid[i];
    const double rm = vh ? rs / (n > 1.0 ? n : 1.0) : 0.0;
    __shared__ double sr[128];
    __shared__ int sc[128];
    sr[i] = rm; sc[i] = vh;
    __syncthreads();
    for (int s = 64; s > 0; s >>= 1) {
        if (i < s) { sr[i] += sr[i + s]; sc[i] += sc[i + s]; }
        __syncthreads();
    }
    if (i == 0) {
        out[0] = (float)(sr[0] / (double)(sc[0] > 1 ? sc[0] : 1));
        double dx = 0.0, dy = 0.0, sb = 0.0, sbf = 0.0;
        float mf = 0.f;
        for (int k = 0; k < 64; ++k) {
            dx += scal64[k * 4 + 0]; dy += scal64[k * 4 + 1];
            sb += scal64[k * 4 + 2]; sbf += scal64[k * 4 + 3];
            mf = fmaxf(mf, __uint_as_float(maxfg64[k]));
        }
        const double maxfg = (double)mf;
        const double maxb = (sb > 0.0) ? 1.0 : 0.0;
        out[1] = (float)((sb - sbf / (maxfg + 1e-6)) / (maxb + 1e-6) / (double)NPIX);
        const double smooth = dx / (double)(2LL * BB * HH * (WW - 1)) +
                              dy / (double)(2LL * BB * (HH - 1) * WW);
        out[3] = (float)smooth;
    }
}

extern "C" void kernel_launch(void* const* d_in, const int* in_sizes, int n_in,
                              void* d_out, int out_size, void* d_ws, size_t ws_size,
                              hipStream_t stream)
{
    const float* flow   = (const float*)d_in[0];
    const int*   masks  = (const int*)d_in[1];
    const float* images = (const float*)d_in[2];
    float* out = (float*)d_out;

    char* ws = (char*)d_ws;
    double*   moments4 = (double*)(ws);             // 0     .. 57344
    double*   res4     = (double*)(ws + 57344);     // 57344 .. 61440
    double*   scal64   = (double*)(ws + 61440);     // 61440 .. 63488
    unsigned* maxfg64  = (unsigned*)(ws + 63488);   // 63488 .. 63744
    float*    params   = (float*)(ws + 63744);      // 63744 .. 66816
    int*      valid    = (int*)(ws + 66816);        // 66816 .. 67328

    hipMemsetAsync(d_ws, 0, 67584, stream);

    moments_kernel<<<dim3(1024), dim3(64), 0, stream>>>(flow, masks, moments4);
    stencil_kernel<<<dim3(NPIX / 2048), dim3(256), 0, stream>>>(
        flow, masks, images, scal64, maxfg64);
    solve_kernel<<<dim3(1), dim3(128), 0, stream>>>(moments4, params, valid, out);
    pass2_kernel<<<dim3(NPIX / 4096), dim3(256), 0, stream>>>(
        flow, masks, params, res4);
    final_kernel<<<dim3(1), dim3(128), 0, stream>>>(
        moments4, res4, valid, scal64, maxfg64, out);
}

// Round 10
// 119.706 us; speedup vs baseline: 2.6716x; 1.2325x over previous
//
#include <hip/hip_runtime.h>
#include <math.h>

#define BB 8
#define HH 512
#define WW 1024
#define HW (HH * WW)          // 524288 = 2^19
#define NPIX (BB * HW)        // 4194304
#define NSEG 16               // segments 1..16 (0 skipped)
#define SUPPRESS 0.1f

// ws layout (bytes):
//   moments4 : double[4][8][16][14] @ 0      (57344)   4-way spread partials
//   res4     : double[4][8][16]     @ 57344  (4096)
//   scal64   : double[64][4]        @ 61440  (2048)    [dx,dy,Sb,Sbf] partials
//   maxfg64  : unsigned[64]         @ 63488  (256)
//   params   : float[128*6]         @ 63744  (3072)
//   valid    : int[128]             @ 66816  (512)

__device__ __forceinline__ float wave_sum(float t) {
    #pragma unroll
    for (int off = 32; off > 0; off >>= 1) t += __shfl_down(t, off);
    return t;
}

#define REP8(M) M(0) M(1) M(2) M(3) M(4) M(5) M(6) M(7)

// ---------------- K_M: segment moments via lane-private LDS bins ----------------
// Main loop (validated r9): lane = column, bins[seg][feat][lane], no atomics,
// no conflicts. r9 epilogue was 224 butterfly wave_sums = 224 x 6-deep
// dependent bpermute chains ~80K cy at 1 wave/SIMD -> dominated the kernel.
// New epilogue: LDS-transpose -- each lane sums one (seg,feat) column over 64
// lanes (staggered index, 2-way bank alias = free), x-folding weight decoded
// from packed nibble constants; 4 rounds cover all 224 pairs; atomics become
// 4 wave-wide f64 atomic instructions.
// moment order: [n,Sx,Sy,Sxx,Sxy,Syy,Su,Sv,Suu,Svv,Sxu,Syu,Sxv,Syv]
// stored bins: 0:n 1:Sy 2:Syy 3:Su 4:Sv 5:Suu 6:Svv 7:Syu 8:Syv
__global__ __launch_bounds__(64) void moments_kernel(
    const float* __restrict__ flow,
    const int*   __restrict__ masks,
    double* __restrict__ moments4)    // [4][8*16*14]
{
    __shared__ float bins[9984];      // 17*9*64 = 9792, padded

    const int lane = threadIdx.x;
    const int bid  = blockIdx.x;      // 1024 = 8 batches x 8 rowgrps x 16 colgrps
    const int colg = bid & 15;
    const int rowg = (bid >> 4) & 7;
    const int b    = bid >> 7;
    const int par  = bid & 3;

    const int c0 = colg * 64;
    const int r0 = rowg * 64;

    const float* fu = flow + (long long)b * (2LL * HW);
    const float* fv = fu + HW;
    const int*   mk = masks + (long long)b * HW;
    const int*   mrow = mk + r0 * WW + c0 + lane;
    const float* urow = fu + r0 * WW + c0 + lane;
    const float* vrow = fv + r0 * WW + c0 + lane;

    #pragma unroll
    for (int i = 0; i < 39; ++i)
        *(float4*)&bins[i * 256 + lane * 4] = make_float4(0.f, 0.f, 0.f, 0.f);

    // depth-2 software prefetch
    int   m0 = mrow[0];
    float u0 = urow[0], v0 = vrow[0];
    int   m1 = mrow[WW];
    float u1 = urow[WW], v1 = vrow[WW];

    #pragma unroll 1
    for (int r = 0; r < 64; r += 2) {
        const int o2 = ((r + 2) & 63) * WW;   // wraps at end; values unused
        const int o3 = ((r + 3) & 63) * WW;
        const int   m2 = mrow[o2];
        const float u2 = urow[o2], v2 = vrow[o2];
        const int   m3 = mrow[o3];
        const float u3 = urow[o3], v3 = vrow[o3];

        {
            const float y = (float)(r0 + r);
            float* bp = &bins[m0 * 576 + lane];
            float b0 = bp[0],   b1 = bp[64],  b2 = bp[128];
            float b3 = bp[192], b4 = bp[256], b5 = bp[320];
            float b6 = bp[384], b7 = bp[448], b8 = bp[512];
            b0 += 1.f;
            b1 += y;
            b2 = fmaf(y, y, b2);
            b3 += u0;
            b4 += v0;
            b5 = fmaf(u0, u0, b5);
            b6 = fmaf(v0, v0, b6);
            b7 = fmaf(y, u0, b7);
            b8 = fmaf(y, v0, b8);
            bp[0] = b0;   bp[64] = b1;  bp[128] = b2;
            bp[192] = b3; bp[256] = b4; bp[320] = b5;
            bp[384] = b6; bp[448] = b7; bp[512] = b8;
        }
        {
            const float y = (float)(r0 + r + 1);
            float* bp = &bins[m1 * 576 + lane];
            float b0 = bp[0],   b1 = bp[64],  b2 = bp[128];
            float b3 = bp[192], b4 = bp[256], b5 = bp[320];
            float b6 = bp[384], b7 = bp[448], b8 = bp[512];
            b0 += 1.f;
            b1 += y;
            b2 = fmaf(y, y, b2);
            b3 += u1;
            b4 += v1;
            b5 = fmaf(u1, u1, b5);
            b6 = fmaf(v1, v1, b6);
            b7 = fmaf(y, u1, b7);
            b8 = fmaf(y, v1, b8);
            bp[0] = b0;   bp[64] = b1;  bp[128] = b2;
            bp[192] = b3; bp[256] = b4; bp[320] = b5;
            bp[384] = b6; bp[448] = b7; bp[512] = b8;
        }
        m0 = m2; u0 = u2; v0 = v2;
        m1 = m3; u1 = u3; v1 = v3;
    }

    // LDS-transpose epilogue: lane p of round rp owns (seg,feat) pair rp*64+lane
    // feat -> src bin nibble table:  [0,0,1,0,1,2,3,4,5,6,3,7,4,8]
    // feat -> x-power nibble table:  [0,1,0,2,1,0,0,0,0,0,1,0,1,0]
    const unsigned long long SRC = 0x84736543210100ULL;
    const unsigned long long PW  = 0x01010000012010ULL;
    double* cell = moments4 + par * 1792 + b * 224;
    #pragma unroll 1
    for (int rp = 0; rp < 4; ++rp) {
        const int p   = rp * 64 + lane;        // 0..255, active if < 224
        const int act = (p < 224);
        const int pc  = act ? p : 0;
        const int segm = pc / 14;              // 0..15 = seg-1
        const int feat = pc - segm * 14;
        const int srcb = (int)((SRC >> (4 * feat)) & 15);
        const int pw   = (int)((PW  >> (4 * feat)) & 15);
        const float* bp = &bins[(segm + 1) * 576 + srcb * 64];
        float acc = 0.f;
        #pragma unroll 8
        for (int l0 = 0; l0 < 64; ++l0) {
            const int l = (l0 + lane) & 63;    // stagger: 2-way bank alias only
            const float xv = (float)(c0 + l);
            const float w = (pw == 0) ? 1.f : ((pw == 1) ? xv : xv * xv);
            acc = fmaf(bp[l], w, acc);
        }
        if (act) atomicAdd(&cell[segm * 14 + feat], (double)acc);
    }
}

// ---------------- K_A: boundary, sobel, smooth ----------------
// r10 change: su/sv LDS staging dropped (-24.6KB -> 33KB LDS -> 4 blocks/CU,
// double the waves/SIMD). u,v neighbors re-read from global (L1/L2-hot).
__global__ __launch_bounds__(256) void stencil_kernel(
    const float* __restrict__ flow,
    const int*   __restrict__ masks,
    const float* __restrict__ images,
    double* __restrict__ scal64,      // [64][4]
    unsigned* __restrict__ maxfg64)   // [64]
{
    __shared__ float         sm[4][1032];
    __shared__ unsigned char smask[4][1032];
    __shared__ float         sg[3][1024];
    __shared__ float         wred[4][5];

    const int tid = threadIdx.x;
    const int lane = tid & 63;
    const long long base = (long long)blockIdx.x * 2048;
    const int b  = (int)(base >> 19);
    const int h0 = (int)((base & (HW - 1)) >> 10);

    const float* fu = flow + (long long)b * (2LL * HW);
    const float* fv = fu + HW;
    const int*   mk = masks + (long long)b * HW;
    const float* i0 = images + (long long)b * (3LL * HW);
    const float* i1 = i0 + HW;
    const float* i2 = i1 + HW;

    const int c4 = tid * 4;
    #pragma unroll
    for (int r = 0; r < 4; ++r) {
        const int gr = h0 - 1 + r;
        const int mr = gr < 0 ? 0 : (gr > HH - 1 ? HH - 1 : gr);
        const int4 mv = *(const int4*)&mk[mr * WW + c4];
        uchar4 mb;
        mb.x = (unsigned char)mv.x; mb.y = (unsigned char)mv.y;
        mb.z = (unsigned char)mv.z; mb.w = (unsigned char)mv.w;
        *(uchar4*)&smask[r][4 + c4] = mb;

        float4 u4 = make_float4(0.f, 0.f, 0.f, 0.f);
        float4 v4 = make_float4(0.f, 0.f, 0.f, 0.f);
        if (gr >= 0 && gr <= HH - 1) {
            u4 = *(const float4*)&fu[gr * WW + c4];
            v4 = *(const float4*)&fv[gr * WW + c4];
        }
        float4 m4;
        m4.x = sqrtf(u4.x * u4.x + v4.x * v4.x);
        m4.y = sqrtf(u4.y * u4.y + v4.y * v4.y);
        m4.z = sqrtf(u4.z * u4.z + v4.z * v4.z);
        m4.w = sqrtf(u4.w * u4.w + v4.w * v4.w);
        *(float4*)&sm[r][4 + c4] = m4;
    }
    #pragma unroll
    for (int r = 0; r < 3; ++r) {
        const int gr = h0 + r;
        float4 g4 = make_float4(0.f, 0.f, 0.f, 0.f);
        if (gr <= HH - 1) {
            const float4 a  = *(const float4*)&i0[gr * WW + c4];
            const float4 bq = *(const float4*)&i1[gr * WW + c4];
            const float4 c  = *(const float4*)&i2[gr * WW + c4];
            g4.x = (a.x + bq.x + c.x) * (1.f / 3.f);
            g4.y = (a.y + bq.y + c.y) * (1.f / 3.f);
            g4.z = (a.z + bq.z + c.z) * (1.f / 3.f);
            g4.w = (a.w + bq.w + c.w) * (1.f / 3.f);
        }
        *(float4*)&sg[r][c4] = g4;
    }
    if (tid < 4) {
        const int gr = h0 - 1 + tid;
        const int mr = gr < 0 ? 0 : (gr > HH - 1 ? HH - 1 : gr);
        smask[tid][3]    = (unsigned char)mk[mr * WW + 0];
        smask[tid][1028] = (unsigned char)mk[mr * WW + WW - 1];
        sm[tid][3] = 0.f;
        sm[tid][1028] = 0.f;
    }
    __syncthreads();

    float a_dx = 0.f, a_dy = 0.f, a_sb = 0.f, a_sbf = 0.f, mfg = 0.f;

    #pragma unroll
    for (int it = 0; it < 8; ++it) {
        const int idx = it * 256 + tid;
        const int lr = idx >> 10;
        const int w  = idx & 1023;
        const int h  = h0 + lr;
        const int cc = 4 + w;

        const int segc = smask[lr + 1][cc];
        int bnd = (smask[lr][cc - 1] != segc) | (smask[lr][cc] != segc) |
                  (smask[lr][cc + 1] != segc) |
                  (smask[lr + 1][cc - 1] != segc) | (smask[lr + 1][cc + 1] != segc) |
                  (smask[lr + 2][cc - 1] != segc) | (smask[lr + 2][cc] != segc) |
                  (smask[lr + 2][cc + 1] != segc);

        const float t00 = sm[lr][cc - 1],     t01 = sm[lr][cc],     t02 = sm[lr][cc + 1];
        const float t10 = sm[lr + 1][cc - 1],                       t12 = sm[lr + 1][cc + 1];
        const float t20 = sm[lr + 2][cc - 1], t21 = sm[lr + 2][cc], t22 = sm[lr + 2][cc + 1];
        const float fgx = (t02 - t00) + 2.f * (t12 - t10) + (t22 - t20);
        const float fgy = (t20 + 2.f * t21 + t22) - (t00 + 2.f * t01 + t02);
        const float fgraw = fabsf(fgx) + fabsf(fgy);
        mfg = fmaxf(mfg, fgraw);
        if (bnd) { a_sb += 1.f; a_sbf += fgraw; }

        const int hw = h * WW + w;
        const float u = fu[hw], v = fv[hw];
        const float g0 = sg[lr][w];
        if (w < WW - 1) {
            const float wgt = expf(-fabsf(sg[lr][w + 1] - g0) * 10.f) * (bnd ? SUPPRESS : 1.f);
            a_dx += (fabsf(fu[hw + 1] - u) + fabsf(fv[hw + 1] - v)) * wgt;
        }
        if (h < HH - 1) {
            const float wgt = expf(-fabsf(sg[lr + 1][w] - g0) * 10.f) * (bnd ? SUPPRESS : 1.f);
            a_dy += (fabsf(fu[hw + WW] - u) + fabsf(fv[hw + WW] - v)) * wgt;
        }
    }

    for (int off = 32; off > 0; off >>= 1) {
        a_dx += __shfl_down(a_dx, off);
        a_dy += __shfl_down(a_dy, off);
        a_sb += __shfl_down(a_sb, off);
        a_sbf += __shfl_down(a_sbf, off);
        mfg = fmaxf(mfg, __shfl_down(mfg, off));
    }
    if (lane == 0) {
        const int wv = tid >> 6;
        wred[wv][0] = a_dx; wred[wv][1] = a_dy; wred[wv][2] = a_sb;
        wred[wv][3] = a_sbf; wred[wv][4] = mfg;
    }
    __syncthreads();
    if (tid == 0) {
        float dx = 0.f, dy = 0.f, sb = 0.f, sbf = 0.f, mf = 0.f;
        for (int i = 0; i < 4; ++i) {
            dx += wred[i][0]; dy += wred[i][1]; sb += wred[i][2];
            sbf += wred[i][3]; mf = fmaxf(mf, wred[i][4]);
        }
        const int sl = blockIdx.x & 63;
        atomicAdd(&scal64[sl * 4 + 0], (double)dx);
        atomicAdd(&scal64[sl * 4 + 1], (double)dy);
        atomicAdd(&scal64[sl * 4 + 2], (double)sb);
        atomicAdd(&scal64[sl * 4 + 3], (double)sbf);
        atomicMax(&maxfg64[sl], __float_as_uint(mf));
    }
}

// ---------------- solve: sum partials, 3x3 normal equations + variance ----------------
__global__ __launch_bounds__(128) void solve_kernel(
    const double* __restrict__ moments4,
    float* __restrict__ params,   // [128][6]
    int* __restrict__ valid,      // [128]
    float* __restrict__ out)
{
    const int i = threadIdx.x;    // (b, seg-1)
    double m[14];
    #pragma unroll
    for (int k = 0; k < 14; ++k) {
        double s = 0.0;
        #pragma unroll
        for (int par = 0; par < 4; ++par) s += moments4[par * 1792 + i * 14 + k];
        m[k] = s;
    }
    const double n = m[0];
    const int vh = (n >= 100.0) ? 1 : 0;
    float p[6] = {0.f, 0.f, 0.f, 0.f, 0.f, 0.f};
    if (vh) {
        double A[3][3] = {{m[3], m[4], m[1]},
                          {m[4], m[5], m[2]},
                          {m[1], m[2], n}};
        double Bm[3][2] = {{m[10], m[12]},
                           {m[11], m[13]},
                           {m[6],  m[7]}};
        for (int k = 0; k < 3; ++k) {
            int piv = k; double mx = fabs(A[k][k]);
            for (int r = k + 1; r < 3; ++r) {
                double a = fabs(A[r][k]);
                if (a > mx) { mx = a; piv = r; }
            }
            if (piv != k) {
                for (int c = 0; c < 3; ++c) { double t = A[k][c]; A[k][c] = A[piv][c]; A[piv][c] = t; }
                for (int c = 0; c < 2; ++c) { double t = Bm[k][c]; Bm[k][c] = Bm[piv][c]; Bm[piv][c] = t; }
            }
            const double inv = 1.0 / A[k][k];
            for (int r = k + 1; r < 3; ++r) {
                const double f = A[r][k] * inv;
                for (int c = k; c < 3; ++c) A[r][c] -= f * A[k][c];
                Bm[r][0] -= f * Bm[k][0];
                Bm[r][1] -= f * Bm[k][1];
            }
        }
        double X[3][2];
        for (int c = 0; c < 2; ++c) {
            X[2][c] = Bm[2][c] / A[2][2];
            X[1][c] = (Bm[1][c] - A[1][2] * X[2][c]) / A[1][1];
            X[0][c] = (Bm[0][c] - A[0][1] * X[1][c] - A[0][2] * X[2][c]) / A[0][0];
        }
        p[0] = (float)X[0][0]; p[1] = (float)X[1][0]; p[2] = (float)X[2][0];
        p[3] = (float)X[0][1]; p[4] = (float)X[1][1]; p[5] = (float)X[2][1];
    }
    valid[i] = vh;
    for (int c = 0; c < 6; ++c) params[i * 6 + c] = p[c];

    const int vv = (n >= 50.0) ? 1 : 0;
    double var = 0.0;
    if (vv) {
        const double ns = (n > 2.0) ? n : 2.0;
        const double var_u = (m[8] - m[6] * m[6] / ns) / (ns - 1.0);
        const double var_v = (m[9] - m[7] * m[7] / ns) / (ns - 1.0);
        var = var_u + var_v;
    }
    __shared__ double svar[128];
    __shared__ int scnt[128];
    svar[i] = var; scnt[i] = vv;
    __syncthreads();
    for (int s = 64; s > 0; s >>= 1) {
        if (i < s) { svar[i] += svar[i + s]; scnt[i] += scnt[i + s]; }
        __syncthreads();
    }
    if (i == 0) out[2] = (float)(svar[0] / (double)(scnt[0] > 1 ? scnt[0] : 1));
}

// ---------------- pass 2: residuals, named-scalar accumulators ----------------
__global__ __launch_bounds__(256) void pass2_kernel(
    const float* __restrict__ flow,
    const int*   __restrict__ masks,
    const float* __restrict__ params,
    double* __restrict__ res4)        // [4][8][16]
{
    __shared__ float sp[17 * 6];      // row 0 = zeros (background)

    const long long base = (long long)blockIdx.x * 4096;
    const int b      = (int)(base >> 19);
    const int hwbase = (int)(base & (HW - 1));
    const int tid    = threadIdx.x;
    const int lane   = tid & 63;

    if (tid < 6) sp[tid] = 0.f;
    if (tid < 96) sp[6 + tid] = params[b * 96 + tid];
    __syncthreads();

    const float* fu = flow + (long long)b * (2LL * HW);
    const float* fv = fu + HW;
    const int*   mk = masks + (long long)b * HW;

#define DECLR(i) float r_##i = 0.f;
    REP8(DECLR)
#define DECLR2(i) float q_##i = 0.f;
    REP8(DECLR2)

    #pragma unroll
    for (int it = 0; it < 4; ++it) {
        const int i4 = hwbase + it * 1024 + tid * 4;
        const int4   m4 = *(const int4*)&mk[i4];
        const float4 u4 = *(const float4*)&fu[i4];
        const float4 v4 = *(const float4*)&fv[i4];
        const int segs[4] = {m4.x, m4.y, m4.z, m4.w};
        const float us[4] = {u4.x, u4.y, u4.z, u4.w};
        const float vs[4] = {v4.x, v4.y, v4.z, v4.w};
        #pragma unroll
        for (int j = 0; j < 4; ++j) {
            const int seg = segs[j];
            const float* pf = &sp[seg * 6];
            const int hw = i4 + j;
            const float x = (float)(hw & 1023), y = (float)((hw & (HW - 1)) >> 10);
            const float du = us[j] - (x * pf[0] + y * pf[1] + pf[2]);
            const float dv = vs[j] - (x * pf[3] + y * pf[4] + pf[5]);
            const float r = sqrtf(du * du + dv * dv);
            const int sr = seg - 1;
#define STEPR(i) r_##i += (sr == i) ? r : 0.f;
            REP8(STEPR)
#define STEPR2(i) q_##i += (sr == 8 + i) ? r : 0.f;
            REP8(STEPR2)
        }
    }

    const int par = blockIdx.x & 3;
    double* rb = &res4[par * 128 + b * 16];
#define FINR(i) { const float s = wave_sum(r_##i); \
    if (lane == 0) atomicAdd(rb + i, (double)s); }
    REP8(FINR)
#define FINR2(i) { const float s = wave_sum(q_##i); \
    if (lane == 0) atomicAdd(rb + 8 + i, (double)s); }
    REP8(FINR2)
}

// ---------------- finalize: homog, sharp, smooth ----------------
__global__ __launch_bounds__(128) void final_kernel(
    const double* __restrict__ moments4,
    const double* __restrict__ res4,
    const int*    __restrict__ valid,
    const double* __restrict__ scal64,
    const unsigned* __restrict__ maxfg64,
    float* __restrict__ out)
{
    const int i = threadIdx.x;
    double n = 0.0, rs = 0.0;
    #pragma unroll
    for (int par = 0; par < 4; ++par) {
        n  += moments4[par * 1792 + i * 14];
        rs += res4[par * 128 + i];
    }
    const int vh = valid[i];
    const double rm = vh ? rs / (n > 1.0 ? n : 1.0) : 0.0;
    __shared__ double sr[128];
    __shared__ int sc[128];
    sr[i] = rm; sc[i] = vh;
    __syncthreads();
    for (int s = 64; s > 0; s >>= 1) {
        if (i < s) { sr[i] += sr[i + s]; sc[i] += sc[i + s]; }
        __syncthreads();
    }
    if (i == 0) {
        out[0] = (float)(sr[0] / (double)(sc[0] > 1 ? sc[0] : 1));
        double dx = 0.0, dy = 0.0, sb = 0.0, sbf = 0.0;
        float mf = 0.f;
        for (int k = 0; k < 64; ++k) {
            dx += scal64[k * 4 + 0]; dy += scal64[k * 4 + 1];
            sb += scal64[k * 4 + 2]; sbf += scal64[k * 4 + 3];
            mf = fmaxf(mf, __uint_as_float(maxfg64[k]));
        }
        const double maxfg = (double)mf;
        const double maxb = (sb > 0.0) ? 1.0 : 0.0;
        out[1] = (float)((sb - sbf / (maxfg + 1e-6)) / (maxb + 1e-6) / (double)NPIX);
        const double smooth = dx / (double)(2LL * BB * HH * (WW - 1)) +
                              dy / (double)(2LL * BB * (HH - 1) * WW);
        out[3] = (float)smooth;
    }
}

extern "C" void kernel_launch(void* const* d_in, const int* in_sizes, int n_in,
                              void* d_out, int out_size, void* d_ws, size_t ws_size,
                              hipStream_t stream)
{
    const float* flow   = (const float*)d_in[0];
    const int*   masks  = (const int*)d_in[1];
    const float* images = (const float*)d_in[2];
    float* out = (float*)d_out;

    char* ws = (char*)d_ws;
    double*   moments4 = (double*)(ws);             // 0     .. 57344
    double*   res4     = (double*)(ws + 57344);     // 57344 .. 61440
    double*   scal64   = (double*)(ws + 61440);     // 61440 .. 63488
    unsigned* maxfg64  = (unsigned*)(ws + 63488);   // 63488 .. 63744
    float*    params   = (float*)(ws + 63744);      // 63744 .. 66816
    int*      valid    = (int*)(ws + 66816);        // 66816 .. 67328

    hipMemsetAsync(d_ws, 0, 67584, stream);

    moments_kernel<<<dim3(1024), dim3(64), 0, stream>>>(flow, masks, moments4);
    stencil_kernel<<<dim3(NPIX / 2048), dim3(256), 0, stream>>>(
        flow, masks, images, scal64, maxfg64);
    solve_kernel<<<dim3(1), dim3(128), 0, stream>>>(moments4, params, valid, out);
    pass2_kernel<<<dim3(NPIX / 4096), dim3(256), 0, stream>>>(
        flow, masks, params, res4);
    final_kernel<<<dim3(1), dim3(128), 0, stream>>>(
        moments4, res4, valid, scal64, maxfg64, out);
}

// Round 11
// 108.408 us; speedup vs baseline: 2.9500x; 1.1042x over previous
//
#include <hip/hip_runtime.h>
#include <math.h>

#define BB 8
#define HH 512
#define WW 1024
#define HW (HH * WW)          // 524288 = 2^19
#define NPIX (BB * HW)        // 4194304
#define NSEG 16               // segments 1..16 (0 skipped)
#define SUPPRESS 0.1f

// ws layout (bytes):
//   moments4 : double[4][8][16][14] @ 0      (57344)   4-way spread partials
//   res4     : double[4][8][16]     @ 57344  (4096)
//   scal64   : double[64][4]        @ 61440  (2048)    [dx,dy,Sb,Sbf] partials
//   maxfg64  : unsigned[64]         @ 63488  (256)
//   params   : float[128*6]         @ 63744  (3072)
//   valid    : int[128]             @ 66816  (512)

__device__ __forceinline__ float wave_sum(float t) {
    #pragma unroll
    for (int off = 32; off > 0; off >>= 1) t += __shfl_down(t, off);
    return t;
}

#define REP8(M) M(0) M(1) M(2) M(3) M(4) M(5) M(6) M(7)

// ---------------- K_M: segment moments via lane-private LDS bins (validated r10) ----------------
__global__ __launch_bounds__(64) void moments_kernel(
    const float* __restrict__ flow,
    const int*   __restrict__ masks,
    double* __restrict__ moments4)    // [4][8*16*14]
{
    __shared__ float bins[9984];      // 17*9*64 = 9792, padded

    const int lane = threadIdx.x;
    const int bid  = blockIdx.x;
    const int colg = bid & 15;
    const int rowg = (bid >> 4) & 7;
    const int b    = bid >> 7;
    const int par  = bid & 3;

    const int c0 = colg * 64;
    const int r0 = rowg * 64;

    const float* fu = flow + (long long)b * (2LL * HW);
    const float* fv = fu + HW;
    const int*   mk = masks + (long long)b * HW;
    const int*   mrow = mk + r0 * WW + c0 + lane;
    const float* urow = fu + r0 * WW + c0 + lane;
    const float* vrow = fv + r0 * WW + c0 + lane;

    #pragma unroll
    for (int i = 0; i < 39; ++i)
        *(float4*)&bins[i * 256 + lane * 4] = make_float4(0.f, 0.f, 0.f, 0.f);

    int   m0 = mrow[0];
    float u0 = urow[0], v0 = vrow[0];
    int   m1 = mrow[WW];
    float u1 = urow[WW], v1 = vrow[WW];

    #pragma unroll 1
    for (int r = 0; r < 64; r += 2) {
        const int o2 = ((r + 2) & 63) * WW;
        const int o3 = ((r + 3) & 63) * WW;
        const int   m2 = mrow[o2];
        const float u2 = urow[o2], v2 = vrow[o2];
        const int   m3 = mrow[o3];
        const float u3 = urow[o3], v3 = vrow[o3];

        {
            const float y = (float)(r0 + r);
            float* bp = &bins[m0 * 576 + lane];
            float b0 = bp[0],   b1 = bp[64],  b2 = bp[128];
            float b3 = bp[192], b4 = bp[256], b5 = bp[320];
            float b6 = bp[384], b7 = bp[448], b8 = bp[512];
            b0 += 1.f;
            b1 += y;
            b2 = fmaf(y, y, b2);
            b3 += u0;
            b4 += v0;
            b5 = fmaf(u0, u0, b5);
            b6 = fmaf(v0, v0, b6);
            b7 = fmaf(y, u0, b7);
            b8 = fmaf(y, v0, b8);
            bp[0] = b0;   bp[64] = b1;  bp[128] = b2;
            bp[192] = b3; bp[256] = b4; bp[320] = b5;
            bp[384] = b6; bp[448] = b7; bp[512] = b8;
        }
        {
            const float y = (float)(r0 + r + 1);
            float* bp = &bins[m1 * 576 + lane];
            float b0 = bp[0],   b1 = bp[64],  b2 = bp[128];
            float b3 = bp[192], b4 = bp[256], b5 = bp[320];
            float b6 = bp[384], b7 = bp[448], b8 = bp[512];
            b0 += 1.f;
            b1 += y;
            b2 = fmaf(y, y, b2);
            b3 += u1;
            b4 += v1;
            b5 = fmaf(u1, u1, b5);
            b6 = fmaf(v1, v1, b6);
            b7 = fmaf(y, u1, b7);
            b8 = fmaf(y, v1, b8);
            bp[0] = b0;   bp[64] = b1;  bp[128] = b2;
            bp[192] = b3; bp[256] = b4; bp[320] = b5;
            bp[384] = b6; bp[448] = b7; bp[512] = b8;
        }
        m0 = m2; u0 = u2; v0 = v2;
        m1 = m3; u1 = u3; v1 = v3;
    }

    const unsigned long long SRC = 0x84736543210100ULL;
    const unsigned long long PW  = 0x01010000012010ULL;
    double* cell = moments4 + par * 1792 + b * 224;
    #pragma unroll 1
    for (int rp = 0; rp < 4; ++rp) {
        const int p   = rp * 64 + lane;
        const int act = (p < 224);
        const int pc  = act ? p : 0;
        const int segm = pc / 14;
        const int feat = pc - segm * 14;
        const int srcb = (int)((SRC >> (4 * feat)) & 15);
        const int pw   = (int)((PW  >> (4 * feat)) & 15);
        const float* bp = &bins[(segm + 1) * 576 + srcb * 64];
        float acc = 0.f;
        #pragma unroll 8
        for (int l0 = 0; l0 < 64; ++l0) {
            const int l = (l0 + lane) & 63;
            const float xv = (float)(c0 + l);
            const float w = (pw == 0) ? 1.f : ((pw == 1) ? xv : xv * xv);
            acc = fmaf(bp[l], w, acc);
        }
        if (act) atomicAdd(&cell[segm * 14 + feat], (double)acc);
    }
}

// ---------------- K_A: boundary, sobel, smooth ----------------
// r11: phase B processes the SAME 8 px (4 cols x 2 rows) each thread staged.
// u,v stay in registers (no phase-B global reads); mask windows are packed
// u64 (1 u32 + 2 byte LDS reads/row); sm windows 1 b128 + 2 scalars/row;
// right-edge u,v via tiny ue/ve LDS arrays. All local arrays fully unrolled
// (constant-indexed -> SROA). ~25 LDS ops per 8 px vs ~150 in r10.
__global__ __launch_bounds__(256, 4) void stencil_kernel(
    const float* __restrict__ flow,
    const int*   __restrict__ masks,
    const float* __restrict__ images,
    double* __restrict__ scal64,      // [64][4]
    unsigned* __restrict__ maxfg64)   // [64]
{
    __shared__ float         sm[4][1032];
    __shared__ unsigned char smask[4][1032];
    __shared__ float         sg[3][1024];
    __shared__ float         ue[2][260];
    __shared__ float         ve[2][260];
    __shared__ float         wred[4][5];

    const int tid = threadIdx.x;
    const int lane = tid & 63;
    const long long base = (long long)blockIdx.x * 2048;
    const int b  = (int)(base >> 19);
    const int h0 = (int)((base & (HW - 1)) >> 10);

    const float* fu = flow + (long long)b * (2LL * HW);
    const float* fv = fu + HW;
    const int*   mk = masks + (long long)b * HW;
    const float* i0 = images + (long long)b * (3LL * HW);
    const float* i1 = i0 + HW;
    const float* i2 = i1 + HW;

    const int c4 = tid * 4;
    float4 ur0, ur1, ur2, vr0, vr1, vr2;   // flow rows h0, h0+1, h0+2

    #pragma unroll
    for (int r = 0; r < 4; ++r) {
        const int gr = h0 - 1 + r;
        const int mr = gr < 0 ? 0 : (gr > HH - 1 ? HH - 1 : gr);
        const int4 mv = *(const int4*)&mk[mr * WW + c4];
        uchar4 mb;
        mb.x = (unsigned char)mv.x; mb.y = (unsigned char)mv.y;
        mb.z = (unsigned char)mv.z; mb.w = (unsigned char)mv.w;
        *(uchar4*)&smask[r][4 + c4] = mb;

        float4 u4 = make_float4(0.f, 0.f, 0.f, 0.f);
        float4 v4 = make_float4(0.f, 0.f, 0.f, 0.f);
        if (gr >= 0 && gr <= HH - 1) {
            u4 = *(const float4*)&fu[gr * WW + c4];
            v4 = *(const float4*)&fv[gr * WW + c4];
        }
        float4 m4;
        m4.x = sqrtf(u4.x * u4.x + v4.x * v4.x);
        m4.y = sqrtf(u4.y * u4.y + v4.y * v4.y);
        m4.z = sqrtf(u4.z * u4.z + v4.z * v4.z);
        m4.w = sqrtf(u4.w * u4.w + v4.w * v4.w);
        *(float4*)&sm[r][4 + c4] = m4;
        if (r == 1) { ur0 = u4; vr0 = v4; }
        else if (r == 2) { ur1 = u4; vr1 = v4; }
        else if (r == 3) { ur2 = u4; vr2 = v4; }
    }
    float4 gr0, gr1, gr2;
    #pragma unroll
    for (int r = 0; r < 3; ++r) {
        const int gr = h0 + r;
        float4 g4 = make_float4(0.f, 0.f, 0.f, 0.f);
        if (gr <= HH - 1) {
            const float4 a  = *(const float4*)&i0[gr * WW + c4];
            const float4 bq = *(const float4*)&i1[gr * WW + c4];
            const float4 c  = *(const float4*)&i2[gr * WW + c4];
            g4.x = (a.x + bq.x + c.x) * (1.f / 3.f);
            g4.y = (a.y + bq.y + c.y) * (1.f / 3.f);
            g4.z = (a.z + bq.z + c.z) * (1.f / 3.f);
            g4.w = (a.w + bq.w + c.w) * (1.f / 3.f);
        }
        *(float4*)&sg[r][c4] = g4;
        if (r == 0) gr0 = g4; else if (r == 1) gr1 = g4; else gr2 = g4;
    }
    ue[0][tid] = ur0.x; ve[0][tid] = vr0.x;
    ue[1][tid] = ur1.x; ve[1][tid] = vr1.x;
    if (tid < 4) {
        const int gr = h0 - 1 + tid;
        const int mr = gr < 0 ? 0 : (gr > HH - 1 ? HH - 1 : gr);
        smask[tid][3]    = (unsigned char)mk[mr * WW + 0];
        smask[tid][1028] = (unsigned char)mk[mr * WW + WW - 1];
        sm[tid][3] = 0.f;
        sm[tid][1028] = 0.f;
    }
    __syncthreads();

    float a_dx = 0.f, a_dy = 0.f, a_sb = 0.f, a_sbf = 0.f, mfg = 0.f;

    #pragma unroll
    for (int lr = 0; lr < 2; ++lr) {
        const int h = h0 + lr;
        // sm windows, rows lr..lr+2 (cols c4-1 .. c4+4)
        float a[3][6];
        unsigned long long kw[3];
        #pragma unroll
        for (int r = 0; r < 3; ++r) {
            const int rr = lr + r;
            const float4 own = *(const float4*)&sm[rr][4 + c4];
            a[r][0] = sm[rr][3 + c4];
            a[r][1] = own.x; a[r][2] = own.y; a[r][3] = own.z; a[r][4] = own.w;
            a[r][5] = sm[rr][8 + c4];
            const unsigned mpk = *(const unsigned*)&smask[rr][4 + c4];
            kw[r] = (unsigned long long)smask[rr][3 + c4]
                  | ((unsigned long long)mpk << 8)
                  | ((unsigned long long)smask[rr][8 + c4] << 40);
        }
        const float4 gc = (lr == 0) ? gr0 : gr1;
        const float4 gd4 = (lr == 0) ? gr1 : gr2;
        const float gRn = (c4 + 4 < WW) ? sg[lr][c4 + 4] : 0.f;
        const float gval[5] = {gc.x, gc.y, gc.z, gc.w, gRn};
        const float4 uc4 = (lr == 0) ? ur0 : ur1;
        const float4 vc4 = (lr == 0) ? vr0 : vr1;
        const float4 ud4 = (lr == 0) ? ur1 : ur2;
        const float4 vd4 = (lr == 0) ? vr1 : vr2;
        const float uc[5] = {uc4.x, uc4.y, uc4.z, uc4.w, ue[lr][tid + 1]};
        const float vc[5] = {vc4.x, vc4.y, vc4.z, vc4.w, ve[lr][tid + 1]};
        const float ud[4] = {ud4.x, ud4.y, ud4.z, ud4.w};
        const float vd[4] = {vd4.x, vd4.y, vd4.z, vd4.w};

        #pragma unroll
        for (int j = 0; j < 4; ++j) {
            const int w = c4 + j;
            const int cseg = (int)((kw[1] >> (8 * (j + 1))) & 255);
            int bnd = (((kw[0] >> (8 * j)) & 255) != (unsigned)cseg)
                    | (((kw[0] >> (8 * (j + 1))) & 255) != (unsigned)cseg)
                    | (((kw[0] >> (8 * (j + 2))) & 255) != (unsigned)cseg)
                    | (((kw[1] >> (8 * j)) & 255) != (unsigned)cseg)
                    | (((kw[1] >> (8 * (j + 2))) & 255) != (unsigned)cseg)
                    | (((kw[2] >> (8 * j)) & 255) != (unsigned)cseg)
                    | (((kw[2] >> (8 * (j + 1))) & 255) != (unsigned)cseg)
                    | (((kw[2] >> (8 * (j + 2))) & 255) != (unsigned)cseg);

            const float fgx = (a[0][j + 2] - a[0][j]) + 2.f * (a[1][j + 2] - a[1][j]) +
                              (a[2][j + 2] - a[2][j]);
            const float fgy = (a[2][j] + 2.f * a[2][j + 1] + a[2][j + 2]) -
                              (a[0][j] + 2.f * a[0][j + 1] + a[0][j + 2]);
            const float fgraw = fabsf(fgx) + fabsf(fgy);
            mfg = fmaxf(mfg, fgraw);
            if (bnd) { a_sb += 1.f; a_sbf += fgraw; }

            const float u = uc[j], v = vc[j], g0 = gval[j];
            if (w < WW - 1) {
                const float wgt = expf(-fabsf(gval[j + 1] - g0) * 10.f) * (bnd ? SUPPRESS : 1.f);
                a_dx += (fabsf(uc[j + 1] - u) + fabsf(vc[j + 1] - v)) * wgt;
            }
            if (h < HH - 1) {
                const float wgt = expf(-fabsf(gd4.x * 0.f + ((const float*)&gd4)[j] - g0) * 10.f) * (bnd ? SUPPRESS : 1.f);
                a_dy += (fabsf(ud[j] - u) + fabsf(vd[j] - v)) * wgt;
            }
        }
    }

    for (int off = 32; off > 0; off >>= 1) {
        a_dx += __shfl_down(a_dx, off);
        a_dy += __shfl_down(a_dy, off);
        a_sb += __shfl_down(a_sb, off);
        a_sbf += __shfl_down(a_sbf, off);
        mfg = fmaxf(mfg, __shfl_down(mfg, off));
    }
    if (lane == 0) {
        const int wv = tid >> 6;
        wred[wv][0] = a_dx; wred[wv][1] = a_dy; wred[wv][2] = a_sb;
        wred[wv][3] = a_sbf; wred[wv][4] = mfg;
    }
    __syncthreads();
    if (tid == 0) {
        float dx = 0.f, dy = 0.f, sb = 0.f, sbf = 0.f, mf = 0.f;
        for (int i = 0; i < 4; ++i) {
            dx += wred[i][0]; dy += wred[i][1]; sb += wred[i][2];
            sbf += wred[i][3]; mf = fmaxf(mf, wred[i][4]);
        }
        const int sl = blockIdx.x & 63;
        atomicAdd(&scal64[sl * 4 + 0], (double)dx);
        atomicAdd(&scal64[sl * 4 + 1], (double)dy);
        atomicAdd(&scal64[sl * 4 + 2], (double)sb);
        atomicAdd(&scal64[sl * 4 + 3], (double)sbf);
        atomicMax(&maxfg64[sl], __float_as_uint(mf));
    }
}

// ---------------- solve: sum partials, 3x3 normal equations + variance ----------------
__global__ __launch_bounds__(128) void solve_kernel(
    const double* __restrict__ moments4,
    float* __restrict__ params,   // [128][6]
    int* __restrict__ valid,      // [128]
    float* __restrict__ out)
{
    const int i = threadIdx.x;    // (b, seg-1)
    double m[14];
    #pragma unroll
    for (int k = 0; k < 14; ++k) {
        double s = 0.0;
        #pragma unroll
        for (int par = 0; par < 4; ++par) s += moments4[par * 1792 + i * 14 + k];
        m[k] = s;
    }
    const double n = m[0];
    const int vh = (n >= 100.0) ? 1 : 0;
    float p[6] = {0.f, 0.f, 0.f, 0.f, 0.f, 0.f};
    if (vh) {
        double A[3][3] = {{m[3], m[4], m[1]},
                          {m[4], m[5], m[2]},
                          {m[1], m[2], n}};
        double Bm[3][2] = {{m[10], m[12]},
                           {m[11], m[13]},
                           {m[6],  m[7]}};
        for (int k = 0; k < 3; ++k) {
            int piv = k; double mx = fabs(A[k][k]);
            for (int r = k + 1; r < 3; ++r) {
                double a = fabs(A[r][k]);
                if (a > mx) { mx = a; piv = r; }
            }
            if (piv != k) {
                for (int c = 0; c < 3; ++c) { double t = A[k][c]; A[k][c] = A[piv][c]; A[piv][c] = t; }
                for (int c = 0; c < 2; ++c) { double t = Bm[k][c]; Bm[k][c] = Bm[piv][c]; Bm[piv][c] = t; }
            }
            const double inv = 1.0 / A[k][k];
            for (int r = k + 1; r < 3; ++r) {
                const double f = A[r][k] * inv;
                for (int c = k; c < 3; ++c) A[r][c] -= f * A[k][c];
                Bm[r][0] -= f * Bm[k][0];
                Bm[r][1] -= f * Bm[k][1];
            }
        }
        double X[3][2];
        for (int c = 0; c < 2; ++c) {
            X[2][c] = Bm[2][c] / A[2][2];
            X[1][c] = (Bm[1][c] - A[1][2] * X[2][c]) / A[1][1];
            X[0][c] = (Bm[0][c] - A[0][1] * X[1][c] - A[0][2] * X[2][c]) / A[0][0];
        }
        p[0] = (float)X[0][0]; p[1] = (float)X[1][0]; p[2] = (float)X[2][0];
        p[3] = (float)X[0][1]; p[4] = (float)X[1][1]; p[5] = (float)X[2][1];
    }
    valid[i] = vh;
    for (int c = 0; c < 6; ++c) params[i * 6 + c] = p[c];

    const int vv = (n >= 50.0) ? 1 : 0;
    double var = 0.0;
    if (vv) {
        const double ns = (n > 2.0) ? n : 2.0;
        const double var_u = (m[8] - m[6] * m[6] / ns) / (ns - 1.0);
        const double var_v = (m[9] - m[7] * m[7] / ns) / (ns - 1.0);
        var = var_u + var_v;
    }
    __shared__ double svar[128];
    __shared__ int scnt[128];
    svar[i] = var; scnt[i] = vv;
    __syncthreads();
    for (int s = 64; s > 0; s >>= 1) {
        if (i < s) { svar[i] += svar[i + s]; scnt[i] += scnt[i + s]; }
        __syncthreads();
    }
    if (i == 0) out[2] = (float)(svar[0] / (double)(scnt[0] > 1 ? scnt[0] : 1));
}

// ---------------- pass 2: residuals, named-scalar accumulators ----------------
__global__ __launch_bounds__(256) void pass2_kernel(
    const float* __restrict__ flow,
    const int*   __restrict__ masks,
    const float* __restrict__ params,
    double* __restrict__ res4)        // [4][8][16]
{
    __shared__ float sp[17 * 6];      // row 0 = zeros (background)

    const long long base = (long long)blockIdx.x * 4096;
    const int b      = (int)(base >> 19);
    const int hwbase = (int)(base & (HW - 1));
    const int tid    = threadIdx.x;
    const int lane   = tid & 63;

    if (tid < 6) sp[tid] = 0.f;
    if (tid < 96) sp[6 + tid] = params[b * 96 + tid];
    __syncthreads();

    const float* fu = flow + (long long)b * (2LL * HW);
    const float* fv = fu + HW;
    const int*   mk = masks + (long long)b * HW;

#define DECLR(i) float r_##i = 0.f;
    REP8(DECLR)
#define DECLR2(i) float q_##i = 0.f;
    REP8(DECLR2)

    #pragma unroll
    for (int it = 0; it < 4; ++it) {
        const int i4 = hwbase + it * 1024 + tid * 4;
        const int4   m4 = *(const int4*)&mk[i4];
        const float4 u4 = *(const float4*)&fu[i4];
        const float4 v4 = *(const float4*)&fv[i4];
        const int segs[4] = {m4.x, m4.y, m4.z, m4.w};
        const float us[4] = {u4.x, u4.y, u4.z, u4.w};
        const float vs[4] = {v4.x, v4.y, v4.z, v4.w};
        #pragma unroll
        for (int j = 0; j < 4; ++j) {
            const int seg = segs[j];
            const float* pf = &sp[seg * 6];
            const int hw = i4 + j;
            const float x = (float)(hw & 1023), y = (float)((hw & (HW - 1)) >> 10);
            const float du = us[j] - (x * pf[0] + y * pf[1] + pf[2]);
            const float dv = vs[j] - (x * pf[3] + y * pf[4] + pf[5]);
            const float r = sqrtf(du * du + dv * dv);
            const int sr = seg - 1;
#define STEPR(i) r_##i += (sr == i) ? r : 0.f;
            REP8(STEPR)
#define STEPR2(i) q_##i += (sr == 8 + i) ? r : 0.f;
            REP8(STEPR2)
        }
    }

    const int par = blockIdx.x & 3;
    double* rb = &res4[par * 128 + b * 16];
#define FINR(i) { const float s = wave_sum(r_##i); \
    if (lane == 0) atomicAdd(rb + i, (double)s); }
    REP8(FINR)
#define FINR2(i) { const float s = wave_sum(q_##i); \
    if (lane == 0) atomicAdd(rb + 8 + i, (double)s); }
    REP8(FINR2)
}

// ---------------- finalize: homog, sharp, smooth ----------------
__global__ __launch_bounds__(128) void final_kernel(
    const double* __restrict__ moments4,
    const double* __restrict__ res4,
    const int*    __restrict__ valid,
    const double* __restrict__ scal64,
    const unsigned* __restrict__ maxfg64,
    float* __restrict__ out)
{
    const int i = threadIdx.x;
    double n = 0.0, rs = 0.0;
    #pragma unroll
    for (int par = 0; par < 4; ++par) {
        n  += moments4[par * 1792 + i * 14];
        rs += res4[par * 128 + i];
    }
    const int vh = valid[i];
    const double rm = vh ? rs / (n > 1.0 ? n : 1.0) : 0.0;
    __shared__ double sr[128];
    __shared__ int sc[128];
    sr[i] = rm; sc[i] = vh;
    __syncthreads();
    for (int s = 64; s > 0; s >>= 1) {
        if (i < s) { sr[i] += sr[i + s]; sc[i] += sc[i + s]; }
        __syncthreads();
    }
    if (i == 0) {
        out[0] = (float)(sr[0] / (double)(sc[0] > 1 ? sc[0] : 1));
        double dx = 0.0, dy = 0.0, sb = 0.0, sbf = 0.0;
        float mf = 0.f;
        for (int k = 0; k < 64; ++k) {
            dx += scal64[k * 4 + 0]; dy += scal64[k * 4 + 1];
            sb += scal64[k * 4 + 2]; sbf += scal64[k * 4 + 3];
            mf = fmaxf(mf, __uint_as_float(maxfg64[k]));
        }
        const double maxfg = (double)mf;
        const double maxb = (sb > 0.0) ? 1.0 : 0.0;
        out[1] = (float)((sb - sbf / (maxfg + 1e-6)) / (maxb + 1e-6) / (double)NPIX);
        const double smooth = dx / (double)(2LL * BB * HH * (WW - 1)) +
                              dy / (double)(2LL * BB * (HH - 1) * WW);
        out[3] = (float)smooth;
    }
}

extern "C" void kernel_launch(void* const* d_in, const int* in_sizes, int n_in,
                              void* d_out, int out_size, void* d_ws, size_t ws_size,
                              hipStream_t stream)
{
    const float* flow   = (const float*)d_in[0];
    const int*   masks  = (const int*)d_in[1];
    const float* images = (const float*)d_in[2];
    float* out = (float*)d_out;

    char* ws = (char*)d_ws;
    double*   moments4 = (double*)(ws);             // 0     .. 57344
    double*   res4     = (double*)(ws + 57344);     // 57344 .. 61440
    double*   scal64   = (double*)(ws + 61440);     // 61440 .. 63488
    unsigned* maxfg64  = (unsigned*)(ws + 63488);   // 63488 .. 63744
    float*    params   = (float*)(ws + 63744);      // 63744 .. 66816
    int*      valid    = (int*)(ws + 66816);        // 66816 .. 67328

    hipMemsetAsync(d_ws, 0, 67584, stream);

    moments_kernel<<<dim3(1024), dim3(64), 0, stream>>>(flow, masks, moments4);
    stencil_kernel<<<dim3(NPIX / 2048), dim3(256), 0, stream>>>(
        flow, masks, images, scal64, maxfg64);
    solve_kernel<<<dim3(1), dim3(128), 0, stream>>>(moments4, params, valid, out);
    pass2_kernel<<<dim3(NPIX / 4096), dim3(256), 0, stream>>>(
        flow, masks, params, res4);
    final_kernel<<<dim3(1), dim3(128), 0, stream>>>(
        moments4, res4, valid, scal64, maxfg64, out);
}